// Round 10
// baseline (202.416 us; speedup 1.0000x reference)
//
#include <hip/hip_runtime.h>

constexpr int BB = 8, CC = 512, TT = 8192;
constexpr int NBLOCK = 512;            // co-resident: 2 blocks/CU x 256 CU
constexpr int BPB = NBLOCK / BB;       // 64 blocks per batch
constexpr int TILE = 64;               // t per tile; each block owns 2 tiles
constexpr float MOM = 0.05f, EPSV = 1e-6f;

typedef float v4f __attribute__((ext_vector_type(4)));

__device__ __forceinline__ void wave_incl_affine(float& A, float& B) {
  const int lane = threadIdx.x & 63;
  #pragma unroll
  for (int off = 1; off < 64; off <<= 1) {
    float pA = __shfl_up(A, off, 64);
    float pB = __shfl_up(B, off, 64);
    if (lane >= off) { B = fmaf(A, pB, B); A *= pA; }
  }
}

// block-wide (512 thr) exclusive affine prefix applied to y0 = 0
__device__ __forceinline__ float block_scan_prev(float A, float B,
                                                 float* wAs, float* wBs) {
  const int lane = threadIdx.x & 63, wid = threadIdx.x >> 6;
  wave_incl_affine(A, B);
  __syncthreads();
  if (lane == 63) { wAs[wid] = A; wBs[wid] = B; }
  __syncthreads();
  float cB = 0.f;
  for (int w = 0; w < wid; ++w) cB = fmaf(wAs[w], cB, wBs[w]);
  float leA = __shfl_up(A, 1, 64);
  float leB = __shfl_up(B, 1, 64);
  if (lane == 0) { leA = 1.f; leB = 0.f; }
  return fmaf(leA, cB, leB);
}

// grid barrier over a provably co-resident grid
__device__ __forceinline__ void grid_barrier(int* c, int expected) {
  __syncthreads();                       // block quiesce (drains vmcnt)
  if (threadIdx.x == 0) {
    __hip_atomic_fetch_add(c, 1, __ATOMIC_RELEASE, __HIP_MEMORY_SCOPE_AGENT);
    while (__hip_atomic_load(c, __ATOMIC_RELAXED, __HIP_MEMORY_SCOPE_AGENT) < expected)
      __builtin_amdgcn_s_sleep(2);
  }
  __syncthreads();
  __builtin_amdgcn_fence(__ATOMIC_ACQUIRE, "agent");
}

__global__ __launch_bounds__(512, 4) void k_all(
    const float* __restrict__ x, const float* __restrict__ g,
    const float* __restrict__ Wa, const float* __restrict__ Wb,
    const float* __restrict__ Wo, const float* __restrict__ Bo,
    float* __restrict__ out,
    float* __restrict__ sa, float* __restrict__ sb, float* __restrict__ sb2,
    float* __restrict__ mean, float* __restrict__ inv,
    int* __restrict__ bar) {
  __shared__ float lwa[CC], lwb[CC], lwo[CC], lbo[CC];
  __shared__ float red[3][8][TILE];
  __shared__ float xw[32];
  __shared__ float wAs[8], wBs[8];

  const int tid = threadIdx.x;
  const int lane = tid & 63;
  const int wid = tid >> 6;
  const int b = blockIdx.x >> 6;             // / BPB
  const int ta = blockIdx.x & (BPB - 1);
  const int tA0 = ta * TILE;                 // [0, 4096)
  const int tB0 = tA0 + 4096;
  const size_t bT = (size_t)b * TT;

  // lane map: t4 = t-quad within tile, csub = channel subgroup
  const int t4 = (lane & 15) << 2;
  const int csub = lane >> 4;
  const int c0 = (wid << 6) + csub;          // first channel; step 4, 16 iters
  const float* xA = x + ((size_t)(b * CC + c0)) * TT + tA0 + t4;

  // ---- softmax over C for Wa, Wb (redundant per block); stage Wo/Bo ----
  {
    float va = Wa[tid], vb = Wb[tid];
    lwo[tid] = Wo[tid];
    lbo[tid] = Bo[tid];
    float ma = va, mb = vb;
    #pragma unroll
    for (int off = 32; off > 0; off >>= 1) {
      ma = fmaxf(ma, __shfl_down(ma, off, 64));
      mb = fmaxf(mb, __shfl_down(mb, off, 64));
    }
    if (lane == 0) { xw[wid] = ma; xw[8 + wid] = mb; }
    __syncthreads();
    ma = xw[0]; mb = xw[8];
    #pragma unroll
    for (int w = 1; w < 8; ++w) { ma = fmaxf(ma, xw[w]); mb = fmaxf(mb, xw[8 + w]); }
    const float ea = expf(va - ma), eb = expf(vb - mb);
    float sA = ea, sB = eb;
    #pragma unroll
    for (int off = 32; off > 0; off >>= 1) {
      sA += __shfl_down(sA, off, 64);
      sB += __shfl_down(sB, off, 64);
    }
    if (lane == 0) { xw[16 + wid] = sA; xw[24 + wid] = sB; }
    __syncthreads();
    sA = xw[16]; sB = xw[24];
    #pragma unroll
    for (int w = 1; w < 8; ++w) { sA += xw[16 + w]; sB += xw[24 + w]; }
    lwa[tid] = ea * (1.f / sA);
    lwb[tid] = eb * (1.f / sB);
  }
  __syncthreads();

  // ---- phase 1, tile A: reduce + keep x in registers (scalar-pinned) ----
  float xs[64];
  {
    v4f aa = {0.f, 0.f, 0.f, 0.f}, ab = aa, aq = aa;
    #pragma unroll
    for (int i = 0; i < 16; ++i) {
      const int c = c0 + (i << 2);
      const v4f xv = *(const v4f*)(xA + ((size_t)(i << 2)) * TT);
      xs[4*i+0] = xv.x; xs[4*i+1] = xv.y; xs[4*i+2] = xv.z; xs[4*i+3] = xv.w;
      const float wac = lwa[c], wbc = lwb[c];
      aa += wac * xv;
      ab += wbc * xv;
      aq += (wbc * xv) * xv;
    }
    #pragma unroll
    for (int k = 0; k < 4; ++k) {
      aa[k] += __shfl_xor(aa[k], 16, 64); ab[k] += __shfl_xor(ab[k], 16, 64);
      aq[k] += __shfl_xor(aq[k], 16, 64);
      aa[k] += __shfl_xor(aa[k], 32, 64); ab[k] += __shfl_xor(ab[k], 32, 64);
      aq[k] += __shfl_xor(aq[k], 32, 64);
    }
    if (lane < 16) {
      *(v4f*)&red[0][wid][t4] = aa;
      *(v4f*)&red[1][wid][t4] = ab;
      *(v4f*)&red[2][wid][t4] = aq;
    }
  }
  // pin every element in a VGPR: loads cannot be sunk past / rematerialized
  #pragma unroll
  for (int i = 0; i < 64; ++i) asm volatile("" : "+v"(xs[i]));
  __syncthreads();
  if (wid == 0) {
    float s0 = 0.f, s1 = 0.f, s2 = 0.f;
    #pragma unroll
    for (int w = 0; w < 8; ++w) {
      s0 += red[0][w][lane]; s1 += red[1][w][lane]; s2 += red[2][w][lane];
    }
    sa[bT + tA0 + lane] = s0; sb[bT + tA0 + lane] = s1; sb2[bT + tA0 + lane] = s2;
  }
  __syncthreads();   // wave0 done reading red before tile B overwrites it

  // ---- phase 1, tile B: streaming reduce (x discarded) ----
  {
    v4f aa = {0.f, 0.f, 0.f, 0.f}, ab = aa, aq = aa;
    #pragma unroll
    for (int i = 0; i < 16; ++i) {
      const int c = c0 + (i << 2);
      const v4f xv = *(const v4f*)(xA + 4096 + ((size_t)(i << 2)) * TT);
      const float wac = lwa[c], wbc = lwb[c];
      aa += wac * xv;
      ab += wbc * xv;
      aq += (wbc * xv) * xv;
    }
    #pragma unroll
    for (int k = 0; k < 4; ++k) {
      aa[k] += __shfl_xor(aa[k], 16, 64); ab[k] += __shfl_xor(ab[k], 16, 64);
      aq[k] += __shfl_xor(aq[k], 16, 64);
      aa[k] += __shfl_xor(aa[k], 32, 64); ab[k] += __shfl_xor(ab[k], 32, 64);
      aq[k] += __shfl_xor(aq[k], 32, 64);
    }
    if (lane < 16) {
      *(v4f*)&red[0][wid][t4] = aa;
      *(v4f*)&red[1][wid][t4] = ab;
      *(v4f*)&red[2][wid][t4] = aq;
    }
  }
  __syncthreads();
  if (wid == 0) {
    float s0 = 0.f, s1 = 0.f, s2 = 0.f;
    #pragma unroll
    for (int w = 0; w < 8; ++w) {
      s0 += red[0][w][lane]; s1 += red[1][w][lane]; s2 += red[2][w][lane];
    }
    sa[bT + tB0 + lane] = s0; sb[bT + tB0 + lane] = s1; sb2[bT + tB0 + lane] = s2;
  }

  grid_barrier(&bar[0], NBLOCK);

  // ---- phase 2: blocks 0..7 scan batch = blockIdx over full T ----
  if (blockIdx.x < BB) {
    const size_t sbase = (size_t)blockIdx.x * TT + (size_t)tid * 16;
    float gt[16];
    float A = 1.f, Bv = 0.f;
    #pragma unroll
    for (int j = 0; j < 16; j += 4) {
      const v4f gq = *(const v4f*)(g  + sbase + j);
      const v4f aq = *(const v4f*)(sa + sbase + j);
      #pragma unroll
      for (int k = 0; k < 4; ++k) {
        const float gg = gq[k] * MOM;
        gt[j + k] = gg;
        const float a = 1.f - gg;
        Bv = fmaf(a, Bv, gg * aq[k]);
        A *= a;
      }
    }
    float m = block_scan_prev(A, Bv, wAs, wBs);

    float A2 = 1.f, B2 = 0.f;
    #pragma unroll
    for (int j = 0; j < 16; j += 4) {
      const v4f aq = *(const v4f*)(sa  + sbase + j);
      const v4f bq = *(const v4f*)(sb  + sbase + j);
      const v4f qq = *(const v4f*)(sb2 + sbase + j);
      v4f mq;
      #pragma unroll
      for (int k = 0; k < 4; ++k) {
        const float gg = gt[j + k], a = 1.f - gg;
        m = fmaf(a, m, gg * aq[k]);
        mq[k] = m;
        const float vi = fmaf(m, m, fmaf(-2.f * m, bq[k], qq[k]));  // sum(wb)=1
        B2 = fmaf(a, B2, gg * vi);
        A2 *= a;
      }
      *(v4f*)(mean + sbase + j) = mq;
    }
    float v = block_scan_prev(A2, B2, wAs, wBs);

    #pragma unroll
    for (int j = 0; j < 16; j += 4) {
      const v4f mq = *(const v4f*)(mean + sbase + j);
      const v4f bq = *(const v4f*)(sb   + sbase + j);
      const v4f qq = *(const v4f*)(sb2  + sbase + j);
      v4f iq;
      #pragma unroll
      for (int k = 0; k < 4; ++k) {
        const float gg = gt[j + k], a = 1.f - gg;
        const float vi = fmaf(mq[k], mq[k], fmaf(-2.f * mq[k], bq[k], qq[k]));
        v = fmaf(a, v, gg * vi);
        iq[k] = rsqrtf(v + EPSV);
      }
      *(v4f*)(inv + sbase + j) = iq;
    }
  }

  grid_barrier(&bar[16], NBLOCK);

  // ---- phase 3, tile A: normalize from registers ----
  {
    const v4f mA = *(const v4f*)(mean + bT + tA0 + t4);
    const v4f iA = *(const v4f*)(inv  + bT + tA0 + t4);
    float* oA = out + ((size_t)(b * CC + c0)) * TT + tA0 + t4;
    #pragma unroll
    for (int i = 0; i < 16; ++i) {
      const int c = c0 + (i << 2);
      v4f xv;
      xv.x = xs[4*i+0]; xv.y = xs[4*i+1]; xv.z = xs[4*i+2]; xv.w = xs[4*i+3];
      v4f o = (xv - mA) * iA * lwo[c] + lbo[c];
      __builtin_nontemporal_store(o, (v4f*)(oA + ((size_t)(i << 2)) * TT));
    }
  }
  // ---- phase 3, tile B: re-read (L3-hopeful), normalize ----
  {
    const v4f mB = *(const v4f*)(mean + bT + tB0 + t4);
    const v4f iB = *(const v4f*)(inv  + bT + tB0 + t4);
    float* oB = out + ((size_t)(b * CC + c0)) * TT + tB0 + t4;
    #pragma unroll
    for (int i = 0; i < 16; ++i) {
      const int c = c0 + (i << 2);
      const v4f xv = *(const v4f*)(xA + 4096 + ((size_t)(i << 2)) * TT);
      v4f o = (xv - mB) * iB * lwo[c] + lbo[c];
      __builtin_nontemporal_store(o, (v4f*)(oB + ((size_t)(i << 2)) * TT));
    }
  }
}

extern "C" void kernel_launch(void* const* d_in, const int* in_sizes, int n_in,
                              void* d_out, int out_size, void* d_ws, size_t ws_size,
                              hipStream_t stream) {
  const float* x  = (const float*)d_in[0];  // (B, C, T)
  const float* g  = (const float*)d_in[1];  // (B, 1, T)
  const float* Wa = (const float*)d_in[2];  // (1, C, 1)
  const float* Wb = (const float*)d_in[3];  // (1, C, 1)
  const float* Wo = (const float*)d_in[4];  // (C, 1, 1)
  const float* Bo = (const float*)d_in[5];  // (C,)
  float* out = (float*)d_out;

  constexpr int BT = BB * TT;
  int* bar    = (int*)d_ws;                 // 2 counters, 64-B spaced
  float* sa   = (float*)(bar + 32);         // BT each
  float* sb   = sa + BT;
  float* sb2  = sb + BT;
  float* mean = sb2 + BT;
  float* inv  = mean + BT;

  hipMemsetAsync(d_ws, 0, 32 * sizeof(int), stream);  // reset barrier counters
  k_all<<<NBLOCK, 512, 0, stream>>>(x, g, Wa, Wb, Wo, Bo, out,
                                    sa, sb, sb2, mean, inv, bar);
}

// Round 11
// 92.175 us; speedup vs baseline: 2.1960x; 2.1960x over previous
//
#include <hip/hip_runtime.h>

constexpr int BB = 8, CC = 512, TT = 8192;
constexpr int LOG_T = 13, LOG_C = 9;
constexpr int TPB = 32;                // t-tiles per batch (256 t each)
constexpr int TILE_T = TT / TPB;       // 256
constexpr float MOM = 0.05f, EPSV = 1e-6f;

typedef float v4f __attribute__((ext_vector_type(4)));

__device__ __forceinline__ void wave_incl_affine(float& A, float& B) {
  const int lane = threadIdx.x & 63;
  #pragma unroll
  for (int off = 1; off < 64; off <<= 1) {
    float pA = __shfl_up(A, off, 64);
    float pB = __shfl_up(B, off, 64);
    if (lane >= off) { B = fmaf(A, pB, B); A *= pA; }
  }
}

// block-wide (512 thr) exclusive affine prefix applied to y0 = 0
__device__ __forceinline__ float block_scan_prev(float A, float B,
                                                 float* wAs, float* wBs) {
  const int lane = threadIdx.x & 63, wid = threadIdx.x >> 6;
  wave_incl_affine(A, B);
  __syncthreads();
  if (lane == 63) { wAs[wid] = A; wBs[wid] = B; }
  __syncthreads();
  float cB = 0.f;
  for (int w = 0; w < wid; ++w) cB = fmaf(wAs[w], cB, wBs[w]);
  float leA = __shfl_up(A, 1, 64);
  float leB = __shfl_up(B, 1, 64);
  if (lane == 0) { leA = 1.f; leB = 0.f; }
  return fmaf(leA, cB, leB);
}

// K1: weighted C-reductions per (b,t); the LAST block of each batch to finish
// also runs the two gated-EMA scans for that batch (no block ever waits).
__global__ __launch_bounds__(512) void k_reduce(
    const float* __restrict__ x, const float* __restrict__ g,
    const float* __restrict__ Wa, const float* __restrict__ Wb,
    float* __restrict__ sa, float* __restrict__ sb, float* __restrict__ sb2,
    float* __restrict__ mean, float* __restrict__ inv,
    int* __restrict__ cnt) {
  __shared__ float lwa[CC], lwb[CC];
  __shared__ float red[3][8][TILE_T];
  __shared__ float xw[32];
  __shared__ float wAs[8], wBs[8];
  __shared__ int is_last_s;

  const int tid = threadIdx.x;
  const int lane = tid & 63;
  const int wid = tid >> 6;
  const int b = blockIdx.x >> 5;           // / TPB
  const int tile = blockIdx.x & (TPB - 1);
  const int t0 = tile * TILE_T;

  // --- softmax over C for Wa, Wb (redundant per block, hidden by loads) ---
  {
    float va = Wa[tid], vb = Wb[tid];
    float ma = va, mb = vb;
    #pragma unroll
    for (int off = 32; off > 0; off >>= 1) {
      ma = fmaxf(ma, __shfl_down(ma, off, 64));
      mb = fmaxf(mb, __shfl_down(mb, off, 64));
    }
    if (lane == 0) { xw[wid] = ma; xw[8 + wid] = mb; }
    __syncthreads();
    ma = xw[0]; mb = xw[8];
    #pragma unroll
    for (int w = 1; w < 8; ++w) { ma = fmaxf(ma, xw[w]); mb = fmaxf(mb, xw[8 + w]); }
    const float ea = expf(va - ma), eb = expf(vb - mb);
    float sA = ea, sB = eb;
    #pragma unroll
    for (int off = 32; off > 0; off >>= 1) {
      sA += __shfl_down(sA, off, 64);
      sB += __shfl_down(sB, off, 64);
    }
    if (lane == 0) { xw[16 + wid] = sA; xw[24 + wid] = sB; }
    __syncthreads();
    sA = xw[16]; sB = xw[24];
    #pragma unroll
    for (int w = 1; w < 8; ++w) { sA += xw[16 + w]; sB += xw[24 + w]; }
    lwa[tid] = ea * (1.f / sA);
    lwb[tid] = eb * (1.f / sB);
  }
  __syncthreads();

  // --- weighted reduction: wave wid covers channels [wid*64, +64),
  //     lane covers t = t0 + lane*4 .. +3 ---
  const int t4 = lane * 4;
  const int cbase = wid * 64;
  const float* xp = x + ((size_t)(b * CC + cbase)) * TT + t0 + t4;
  float a0=0,a1=0,a2=0,a3=0, b0=0,b1=0,b2=0,b3=0, q0=0,q1=0,q2=0,q3=0;
  #pragma unroll 8
  for (int cc = 0; cc < 64; ++cc) {
    float4 xv = *(const float4*)(xp + (size_t)cc * TT);
    const float wac = lwa[cbase + cc], wbc = lwb[cbase + cc];
    a0 = fmaf(wac, xv.x, a0); a1 = fmaf(wac, xv.y, a1);
    a2 = fmaf(wac, xv.z, a2); a3 = fmaf(wac, xv.w, a3);
    b0 = fmaf(wbc, xv.x, b0); b1 = fmaf(wbc, xv.y, b1);
    b2 = fmaf(wbc, xv.z, b2); b3 = fmaf(wbc, xv.w, b3);
    q0 = fmaf(wbc * xv.x, xv.x, q0); q1 = fmaf(wbc * xv.y, xv.y, q1);
    q2 = fmaf(wbc * xv.z, xv.z, q2); q3 = fmaf(wbc * xv.w, xv.w, q3);
  }
  red[0][wid][t4+0]=a0; red[0][wid][t4+1]=a1; red[0][wid][t4+2]=a2; red[0][wid][t4+3]=a3;
  red[1][wid][t4+0]=b0; red[1][wid][t4+1]=b1; red[1][wid][t4+2]=b2; red[1][wid][t4+3]=b3;
  red[2][wid][t4+0]=q0; red[2][wid][t4+1]=q1; red[2][wid][t4+2]=q2; red[2][wid][t4+3]=q3;
  __syncthreads();

  if (tid < 64) {
    const int o = tid * 4;
    float oa[4] = {0,0,0,0}, ob[4] = {0,0,0,0}, oq[4] = {0,0,0,0};
    #pragma unroll
    for (int w = 0; w < 8; ++w) {
      #pragma unroll
      for (int k = 0; k < 4; ++k) {
        oa[k] += red[0][w][o+k];
        ob[k] += red[1][w][o+k];
        oq[k] += red[2][w][o+k];
      }
    }
    const size_t dst = (size_t)b * TT + t0 + o;
    *(float4*)(sa  + dst) = make_float4(oa[0], oa[1], oa[2], oa[3]);
    *(float4*)(sb  + dst) = make_float4(ob[0], ob[1], ob[2], ob[3]);
    *(float4*)(sb2 + dst) = make_float4(oq[0], oq[1], oq[2], oq[3]);
  }
  __syncthreads();  // all stat stores issued by all waves

  // --- last-arriver election (release makes our stats visible first) ---
  if (tid == 0) {
    const int old = __hip_atomic_fetch_add(&cnt[b * 16], 1, __ATOMIC_RELEASE,
                                           __HIP_MEMORY_SCOPE_AGENT);
    is_last_s = (old == TPB - 1);
  }
  __syncthreads();
  if (!is_last_s) return;

  // --- this block is last for batch b: run both EMA scans over full T ---
  __builtin_amdgcn_fence(__ATOMIC_ACQUIRE, "agent");
  constexpr int CH = 16;  // 512 thr * 16 = 8192
  const size_t base = (size_t)b * TT + (size_t)tid * CH;
  float gt[CH], pa[CH];

  float A = 1.f, Bv = 0.f;
  #pragma unroll
  for (int j = 0; j < CH; j += 4) {
    float gv[4]; *(float4*)gv = *(const float4*)(g  + base + j);
    float av[4]; *(float4*)av = *(const float4*)(sa + base + j);
    #pragma unroll
    for (int k = 0; k < 4; ++k) {
      const float gg = gv[k] * MOM;
      gt[j + k] = gg;
      const float p = gg * av[k];
      pa[j + k] = p;
      const float a = 1.f - gg;
      A *= a;
      Bv = fmaf(a, Bv, p);
    }
  }
  float m = block_scan_prev(A, Bv, wAs, wBs);

  float A2 = 1.f, B2 = 0.f;
  #pragma unroll
  for (int j = 0; j < CH; j += 4) {
    float bv[4]; *(float4*)bv = *(const float4*)(sb  + base + j);
    float qv[4]; *(float4*)qv = *(const float4*)(sb2 + base + j);
    float m4[4];
    #pragma unroll
    for (int k = 0; k < 4; ++k) {
      const float a = 1.f - gt[j + k];
      m = fmaf(a, m, pa[j + k]);
      m4[k] = m;
      const float vi = fmaf(m, m, fmaf(-2.f * m, bv[k], qv[k]));  // sum(wb)=1
      const float pv = gt[j + k] * vi;
      pa[j + k] = pv;
      A2 *= a;
      B2 = fmaf(a, B2, pv);
    }
    *(float4*)(mean + base + j) = *(float4*)m4;
  }
  float v = block_scan_prev(A2, B2, wAs, wBs);

  #pragma unroll
  for (int j = 0; j < CH; j += 4) {
    float i4[4];
    #pragma unroll
    for (int k = 0; k < 4; ++k) {
      v = fmaf(1.f - gt[j + k], v, pa[j + k]);
      i4[k] = rsqrtf(v + EPSV);
    }
    *(float4*)(inv + base + j) = *(float4*)i4;
  }
}

// K2: pointwise normalize, FORWARD traversal (R5 proved reverse hurts),
// non-temporal stores so out never allocates in L3 (keeps x resident).
__global__ __launch_bounds__(256) void k_out(const float* __restrict__ x,
                                             const float* __restrict__ mean,
                                             const float* __restrict__ inv,
                                             const float* __restrict__ wo,
                                             const float* __restrict__ bo,
                                             float* __restrict__ out) {
  const size_t base4 = (size_t)blockIdx.x * 1024 + threadIdx.x;
  #pragma unroll
  for (int j = 0; j < 4; ++j) {
    const size_t idx = base4 + (size_t)j * 256;
    const size_t flat = idx * 4;
    const int t = (int)(flat & (TT - 1));
    const size_t rem = flat >> LOG_T;
    const int c = (int)(rem & (CC - 1));
    const int b = (int)(rem >> LOG_C);
    float4 xv = *(const float4*)(x + flat);
    const size_t mi = ((size_t)b << LOG_T) + t;
    float4 m4 = *(const float4*)(mean + mi);
    float4 i4 = *(const float4*)(inv + mi);
    const float w = wo[c], bb = bo[c];
    v4f o;
    o.x = fmaf((xv.x - m4.x) * i4.x, w, bb);
    o.y = fmaf((xv.y - m4.y) * i4.y, w, bb);
    o.z = fmaf((xv.z - m4.z) * i4.z, w, bb);
    o.w = fmaf((xv.w - m4.w) * i4.w, w, bb);
    __builtin_nontemporal_store(o, (v4f*)(out + flat));
  }
}

extern "C" void kernel_launch(void* const* d_in, const int* in_sizes, int n_in,
                              void* d_out, int out_size, void* d_ws, size_t ws_size,
                              hipStream_t stream) {
  const float* x  = (const float*)d_in[0];  // (B, C, T)
  const float* g  = (const float*)d_in[1];  // (B, 1, T)
  const float* Wa = (const float*)d_in[2];  // (1, C, 1)
  const float* Wb = (const float*)d_in[3];  // (1, C, 1)
  const float* Wo = (const float*)d_in[4];  // (C, 1, 1)
  const float* Bo = (const float*)d_in[5];  // (C,)
  float* out = (float*)d_out;

  constexpr int BT = BB * TT;
  int* cnt    = (int*)d_ws;                 // BB counters, 64-B spaced
  float* sa   = (float*)(cnt + BB * 16);    // BT
  float* sb   = sa + BT;
  float* sb2  = sb + BT;
  float* mean = sb2 + BT;
  float* inv  = mean + BT;

  hipMemsetAsync(d_ws, 0, BB * 16 * sizeof(int), stream);  // reset counters
  k_reduce<<<BB * TPB, 512, 0, stream>>>(x, g, Wa, Wb, sa, sb, sb2, mean, inv, cnt);
  k_out<<<8192, 256, 0, stream>>>(x, mean, inv, Wo, Bo, out);
}

// Round 12
// 83.972 us; speedup vs baseline: 2.4105x; 1.0977x over previous
//
#include <hip/hip_runtime.h>

constexpr int BB = 8, CC = 512, TT = 8192;
constexpr float MOM = 0.05f, EPSV = 1e-6f;

typedef float v4f __attribute__((ext_vector_type(4)));

__device__ __forceinline__ void wave_incl_affine(float& A, float& B) {
  const int lane = threadIdx.x & 63;
  #pragma unroll
  for (int off = 1; off < 64; off <<= 1) {
    float pA = __shfl_up(A, off, 64);
    float pB = __shfl_up(B, off, 64);
    if (lane >= off) { B = fmaf(A, pB, B); A *= pA; }
  }
}

// block-wide exclusive affine prefix applied to y0 = 0 (NW waves)
template <int NW>
__device__ __forceinline__ float block_scan_prev(float A, float B,
                                                 float* wAs, float* wBs) {
  const int lane = threadIdx.x & 63, wid = threadIdx.x >> 6;
  wave_incl_affine(A, B);
  __syncthreads();
  if (lane == 63) { wAs[wid] = A; wBs[wid] = B; }
  __syncthreads();
  float cB = 0.f;
  for (int w = 0; w < wid; ++w) cB = fmaf(wAs[w], cB, wBs[w]);
  float leA = __shfl_up(A, 1, 64);
  float leB = __shfl_up(B, 1, 64);
  if (lane == 0) { leA = 1.f; leB = 0.f; }
  return fmaf(leA, cB, leB);
}

// K1: per (b,t) weighted reductions over C -> sa, sb, sb2.
// 256 blocks x 512 thr; wave wid covers channels [wid*64, +64),
// lane covers t = t0 + lane*4 (float4). 1 KiB/wave/instr, coalesced.
__global__ __launch_bounds__(512) void k_reduce(
    const float* __restrict__ x, const float* __restrict__ Wa,
    const float* __restrict__ Wb, float* __restrict__ sa,
    float* __restrict__ sb, float* __restrict__ sb2) {
  __shared__ float lwa[CC], lwb[CC];
  __shared__ float red[3][8][256];
  __shared__ float xw[32];

  const int tid = threadIdx.x;
  const int lane = tid & 63;
  const int wid = tid >> 6;
  const int b = blockIdx.x >> 5;           // 32 t-tiles per batch
  const int t0 = (blockIdx.x & 31) * 256;

  // softmax over C for Wa, Wb (redundant per block)
  {
    float va = Wa[tid], vb = Wb[tid];
    float ma = va, mb = vb;
    #pragma unroll
    for (int off = 32; off > 0; off >>= 1) {
      ma = fmaxf(ma, __shfl_down(ma, off, 64));
      mb = fmaxf(mb, __shfl_down(mb, off, 64));
    }
    if (lane == 0) { xw[wid] = ma; xw[8 + wid] = mb; }
    __syncthreads();
    ma = xw[0]; mb = xw[8];
    #pragma unroll
    for (int w = 1; w < 8; ++w) { ma = fmaxf(ma, xw[w]); mb = fmaxf(mb, xw[8 + w]); }
    const float ea = expf(va - ma), eb = expf(vb - mb);
    float sA = ea, sB = eb;
    #pragma unroll
    for (int off = 32; off > 0; off >>= 1) {
      sA += __shfl_down(sA, off, 64);
      sB += __shfl_down(sB, off, 64);
    }
    if (lane == 0) { xw[16 + wid] = sA; xw[24 + wid] = sB; }
    __syncthreads();
    sA = xw[16]; sB = xw[24];
    #pragma unroll
    for (int w = 1; w < 8; ++w) { sA += xw[16 + w]; sB += xw[24 + w]; }
    lwa[tid] = ea * (1.f / sA);
    lwb[tid] = eb * (1.f / sB);
  }
  __syncthreads();

  const int t4 = lane * 4;
  const int cbase = wid * 64;
  const float* xp = x + ((size_t)(b * CC + cbase)) * TT + t0 + t4;
  float a0=0,a1=0,a2=0,a3=0, b0=0,b1=0,b2=0,b3=0, q0=0,q1=0,q2=0,q3=0;
  #pragma unroll 8
  for (int cc = 0; cc < 64; ++cc) {
    float4 xv = *(const float4*)(xp + (size_t)cc * TT);
    const float wac = lwa[cbase + cc], wbc = lwb[cbase + cc];
    a0 = fmaf(wac, xv.x, a0); a1 = fmaf(wac, xv.y, a1);
    a2 = fmaf(wac, xv.z, a2); a3 = fmaf(wac, xv.w, a3);
    b0 = fmaf(wbc, xv.x, b0); b1 = fmaf(wbc, xv.y, b1);
    b2 = fmaf(wbc, xv.z, b2); b3 = fmaf(wbc, xv.w, b3);
    q0 = fmaf(wbc * xv.x, xv.x, q0); q1 = fmaf(wbc * xv.y, xv.y, q1);
    q2 = fmaf(wbc * xv.z, xv.z, q2); q3 = fmaf(wbc * xv.w, xv.w, q3);
  }
  red[0][wid][t4+0]=a0; red[0][wid][t4+1]=a1; red[0][wid][t4+2]=a2; red[0][wid][t4+3]=a3;
  red[1][wid][t4+0]=b0; red[1][wid][t4+1]=b1; red[1][wid][t4+2]=b2; red[1][wid][t4+3]=b3;
  red[2][wid][t4+0]=q0; red[2][wid][t4+1]=q1; red[2][wid][t4+2]=q2; red[2][wid][t4+3]=q3;
  __syncthreads();

  if (tid < 64) {
    const int o = tid * 4;
    float oa[4] = {0,0,0,0}, ob[4] = {0,0,0,0}, oq[4] = {0,0,0,0};
    #pragma unroll
    for (int w = 0; w < 8; ++w) {
      #pragma unroll
      for (int k = 0; k < 4; ++k) {
        oa[k] += red[0][w][o+k];
        ob[k] += red[1][w][o+k];
        oq[k] += red[2][w][o+k];
      }
    }
    const size_t dst = (size_t)b * TT + t0 + o;
    *(float4*)(sa  + dst) = make_float4(oa[0], oa[1], oa[2], oa[3]);
    *(float4*)(sb  + dst) = make_float4(ob[0], ob[1], ob[2], ob[3]);
    *(float4*)(sb2 + dst) = make_float4(oq[0], oq[1], oq[2], oq[3]);
  }
}

// K2: per-batch gated-EMA scans over T (8 blocks x 1024 thr, CH=8)
__global__ __launch_bounds__(1024) void k_scan(const float* __restrict__ g,
                                               const float* __restrict__ sa,
                                               const float* __restrict__ sb,
                                               const float* __restrict__ sb2,
                                               float* __restrict__ mean,
                                               float* __restrict__ inv) {
  constexpr int CH = 8;
  __shared__ float wAs[16], wBs[16];
  const int tid = threadIdx.x;
  const size_t base = (size_t)blockIdx.x * TT + (size_t)tid * CH;

  float gv[CH], av[CH], bv[CH], qv[CH];
  *(v4f*)(gv)     = *(const v4f*)(g   + base);
  *(v4f*)(gv + 4) = *(const v4f*)(g   + base + 4);
  *(v4f*)(av)     = *(const v4f*)(sa  + base);
  *(v4f*)(av + 4) = *(const v4f*)(sa  + base + 4);
  *(v4f*)(bv)     = *(const v4f*)(sb  + base);
  *(v4f*)(bv + 4) = *(const v4f*)(sb  + base + 4);
  *(v4f*)(qv)     = *(const v4f*)(sb2 + base);
  *(v4f*)(qv + 4) = *(const v4f*)(sb2 + base + 4);

  float gt[CH], pa[CH];
  float A = 1.f, Bv = 0.f;
  #pragma unroll
  for (int j = 0; j < CH; ++j) {
    const float gg = gv[j] * MOM;
    gt[j] = gg;
    const float p = gg * av[j];
    pa[j] = p;
    const float a = 1.f - gg;
    A *= a;
    Bv = fmaf(a, Bv, p);
  }
  float m = block_scan_prev<16>(A, Bv, wAs, wBs);

  float m4[CH];
  float A2 = 1.f, B2 = 0.f;
  #pragma unroll
  for (int j = 0; j < CH; ++j) {
    const float a = 1.f - gt[j];
    m = fmaf(a, m, pa[j]);
    m4[j] = m;
    const float vi = fmaf(m, m, fmaf(-2.f * m, bv[j], qv[j]));  // sum(wb)=1
    const float pv = gt[j] * vi;
    pa[j] = pv;
    A2 *= a;
    B2 = fmaf(a, B2, pv);
  }
  *(v4f*)(mean + base)     = *(v4f*)(m4);
  *(v4f*)(mean + base + 4) = *(v4f*)(m4 + 4);

  float v = block_scan_prev<16>(A2, B2, wAs, wBs);

  float i4[CH];
  #pragma unroll
  for (int j = 0; j < CH; ++j) {
    v = fmaf(1.f - gt[j], v, pa[j]);
    i4[j] = rsqrtf(v + EPSV);
  }
  *(v4f*)(inv + base)     = *(v4f*)(i4);
  *(v4f*)(inv + base + 4) = *(v4f*)(i4 + 4);
}

// K3: normalize. Block = (b, c-half, 256-t tile); lane owns one t-quad and
// loads mean/inv ONCE into VGPRs, then loops 32 channels at stride TT.
// wo[c]/bo[c] are wave-uniform -> scalar loads. 512 blocks = 2/CU.
__global__ __launch_bounds__(512) void k_out(const float* __restrict__ x,
                                             const float* __restrict__ mean,
                                             const float* __restrict__ inv,
                                             const float* __restrict__ wo,
                                             const float* __restrict__ bo,
                                             float* __restrict__ out) {
  const int lane = threadIdx.x & 63;
  const int wid = threadIdx.x >> 6;
  const int tt = blockIdx.x & 31;
  const int ch = (blockIdx.x >> 5) & 1;
  const int b  = blockIdx.x >> 6;
  const int t0 = tt * 256;
  const int t4 = lane * 4;
  const int cbase = ch * 256 + wid * 32;

  const size_t mi = (size_t)b * TT + t0 + t4;
  const v4f m4 = *(const v4f*)(mean + mi);
  const v4f i4 = *(const v4f*)(inv + mi);

  const size_t off0 = ((size_t)(b * CC + cbase)) * TT + t0 + t4;
  const float* xp = x + off0;
  float* op = out + off0;

  #pragma unroll 8
  for (int cc = 0; cc < 32; ++cc) {
    const int c = cbase + cc;
    const v4f xv = *(const v4f*)(xp + (size_t)cc * TT);
    const v4f o = (xv - m4) * i4 * wo[c] + bo[c];
    __builtin_nontemporal_store(o, (v4f*)(op + (size_t)cc * TT));
  }
}

extern "C" void kernel_launch(void* const* d_in, const int* in_sizes, int n_in,
                              void* d_out, int out_size, void* d_ws, size_t ws_size,
                              hipStream_t stream) {
  const float* x  = (const float*)d_in[0];  // (B, C, T)
  const float* g  = (const float*)d_in[1];  // (B, 1, T)
  const float* Wa = (const float*)d_in[2];  // (1, C, 1)
  const float* Wb = (const float*)d_in[3];  // (1, C, 1)
  const float* Wo = (const float*)d_in[4];  // (C, 1, 1)
  const float* Bo = (const float*)d_in[5];  // (C,)
  float* out = (float*)d_out;

  constexpr int BT = BB * TT;
  float* ws   = (float*)d_ws;
  float* sa   = ws;               // B*T
  float* sb   = sa + BT;
  float* sb2  = sb + BT;
  float* mean = sb2 + BT;
  float* inv  = mean + BT;        // total ~1.25 MiB

  k_reduce<<<BB * 32, 512, 0, stream>>>(x, Wa, Wb, sa, sb, sb2);
  k_scan<<<BB, 1024, 0, stream>>>(g, sa, sb, sb2, mean, inv);
  k_out<<<BB * 2 * 32, 512, 0, stream>>>(x, mean, inv, Wo, Bo, out);
}